// Round 4
// baseline (29890.509 us; speedup 1.0000x reference)
//
#include <hip/hip_runtime.h>
#include <hip/hip_bf16.h>

#define NL 4
#define NB 64
#define NT 512
#define NH 1024
#define N3H 3072
#define SLOT 65536   // elements per frag-major slot: 4*32*64*8 (= 128 KB)

typedef __attribute__((ext_vector_type(8))) short short8;
typedef __attribute__((ext_vector_type(4))) float floatx4;

__device__ __forceinline__ short8 ld8(const __hip_bfloat16* p) {
  return *(const short8*)p;
}

// frag-major element offset inside a slot for (batch b, unit k):
// [w=b>>4][kc=k>>5][lane'=((k&31)>>3)*16 + (b&15)][j=k&7]
__device__ __forceinline__ size_t fm_off(int b, int k) {
  return (size_t)(b >> 4) * 16384 + (size_t)(k >> 5) * 512 +
         (size_t)((((k & 31) >> 3) * 16) + (b & 15)) * 8 + (k & 7);
}

// ---------------- prep kernels ----------------

__global__ void conv_w_kernel(const float* __restrict__ w_ih,
                              const float* __restrict__ w_hh,
                              __hip_bfloat16* __restrict__ wih_b,
                              __hip_bfloat16* __restrict__ whh_hi,
                              __hip_bfloat16* __restrict__ whh_lo_n) {
  size_t i = (size_t)blockIdx.x * 256 + threadIdx.x;
  if (i >= (size_t)NL * N3H * NH) return;
  wih_b[i] = __float2bfloat16(w_ih[i]);
  float v = w_hh[i];
  __hip_bfloat16 hi = __float2bfloat16(v);
  whh_hi[i] = hi;
  size_t l = i / ((size_t)N3H * NH);
  size_t rem = i - l * ((size_t)N3H * NH);
  size_t row = rem / NH;
  if (row >= (size_t)2 * NH) {
    size_t k = rem - row * NH;
    whh_lo_n[(l * NH + (row - 2 * NH)) * NH + k] =
        __float2bfloat16(v - __bfloat162float(hi));
  }
}

// x[t][b][k] fp32 -> frag-major bf16 at slot t+1 of seqA
__global__ void conv_x_kernel(const float* __restrict__ x,
                              __hip_bfloat16* __restrict__ seq) {
  size_t i = (size_t)blockIdx.x * 256 + threadIdx.x;
  if (i >= (size_t)NT * NB * NH) return;
  int t = (int)(i >> 16);
  int b = (int)((i >> 10) & 63);
  int k = (int)(i & 1023);
  seq[(size_t)(t + 1) * SLOT + fm_off(b, k)] = __float2bfloat16(x[i]);
}

// h0 -> d_out fp32 master ; zero flags
__global__ void init_out_kernel(const float* __restrict__ h0,
                                float* __restrict__ out,
                                int* __restrict__ flags) {
  size_t i = (size_t)blockIdx.x * 256 + threadIdx.x;
  if (i < 256) flags[i] = 0;
  if (i >= (size_t)NL * NB * NH) return;
  out[i] = h0[i];
}

// h0 layer slice -> frag-major slot 0 of the layer's output buffer
__global__ void init_hbf_kernel(const float* __restrict__ h0_layer,
                                __hip_bfloat16* __restrict__ slot0) {
  int i = blockIdx.x * 256 + threadIdx.x;
  if (i >= NB * NH) return;
  int b = i >> 10, k = i & 1023;
  slot0[fm_off(b, k)] = __float2bfloat16(h0_layer[i]);
}

// ---------------- gi GEMM: C[M][3072] = A @ W^T + bih, A frag-major --------
// A slot base = Aslot (chunk's first input slot); row m -> t=m>>6, b=m&63
__global__ __launch_bounds__(256) void gemm_gi_kernel(
    const __hip_bfloat16* __restrict__ Aslot,
    const __hip_bfloat16* __restrict__ Wb,
    const float* __restrict__ bih,
    float* __restrict__ C) {
  __shared__ short lA[128 * 32];
  __shared__ short lB[128 * 32];
  const int tid = threadIdx.x;
  const int wave = tid >> 6, lane = tid & 63;
  const int l15 = lane & 15, quad = lane >> 4;
  const int m0 = blockIdx.x * 128;
  const int n0 = blockIdx.y * 128;
  const int wm = (wave >> 1) * 64, wn = (wave & 1) * 64;

  const int r1 = tid >> 2, c1 = (tid & 3) * 8;
  // frag-major A: rows m0+r1 (t = m0>>6) and m0+r1+64 (t+1)
  const __hip_bfloat16* Abase = Aslot + (size_t)(m0 >> 6) * SLOT
      + (size_t)(r1 >> 4) * 16384 + (size_t)((c1 >> 3) * 16 + (r1 & 15)) * 8;
  const __hip_bfloat16* Brow0 = Wb + (size_t)(n0 + r1) * NH + c1;
  const __hip_bfloat16* Brow1 = Wb + (size_t)(n0 + r1 + 64) * NH + c1;

  floatx4 z4 = {0.f, 0.f, 0.f, 0.f};
  floatx4 acc[4][4];
#pragma unroll
  for (int mi = 0; mi < 4; ++mi)
#pragma unroll
    for (int ni = 0; ni < 4; ++ni) acc[mi][ni] = z4;

  for (int kt = 0; kt < 32; ++kt) {
    short8 a0 = ld8(Abase + (size_t)kt * 512);
    short8 a1 = ld8(Abase + SLOT + (size_t)kt * 512);
    short8 b0 = ld8(Brow0 + kt * 32), b1 = ld8(Brow1 + kt * 32);
    __syncthreads();
    *(short8*)(lA + tid * 8) = a0;
    *(short8*)(lA + (tid + 256) * 8) = a1;
    *(short8*)(lB + tid * 8) = b0;
    *(short8*)(lB + (tid + 256) * 8) = b1;
    __syncthreads();
    short8 af[4], bf[4];
#pragma unroll
    for (int mi = 0; mi < 4; ++mi)
      af[mi] = *(short8*)(lA + (wm + mi * 16 + l15) * 32 + quad * 8);
#pragma unroll
    for (int ni = 0; ni < 4; ++ni)
      bf[ni] = *(short8*)(lB + (wn + ni * 16 + l15) * 32 + quad * 8);
#pragma unroll
    for (int mi = 0; mi < 4; ++mi)
#pragma unroll
      for (int ni = 0; ni < 4; ++ni)
        acc[mi][ni] =
            __builtin_amdgcn_mfma_f32_16x16x32_bf16(af[mi], bf[ni], acc[mi][ni], 0, 0, 0);
  }

  const int crow = m0 + wm + quad * 4;
#pragma unroll
  for (int ni = 0; ni < 4; ++ni) {
    const int col = n0 + wn + ni * 16 + l15;
    const float bias = bih[col];
#pragma unroll
    for (int mi = 0; mi < 4; ++mi)
#pragma unroll
      for (int r = 0; r < 4; ++r)
        C[(size_t)(crow + mi * 16 + r) * N3H + col] = acc[mi][ni][r] + bias;
  }
}

// ---------------- recurrent chunk kernel ----------------
// exch = output seq buffer + chunk base slot (frag-major). Consumer reads slot
// tc fully coalesced (1 KB per wave-instr); producer writes its contiguous
// 512 B region of slot tc+1 via LDS transpose + 32-lane dwordx4 write-through.
// Dense flags: one poll instr = 4 line transactions.
__global__ __launch_bounds__(64) void gru_persist_kernel(
    const __hip_bfloat16* __restrict__ whh_hi_l,  // [3072][1024]
    const __hip_bfloat16* __restrict__ whh_lo_l,  // [1024][1024] n-gate lo
    const float* __restrict__ gi_c,               // [TC][64][3072]
    const float* __restrict__ bhh_l,              // [3072]
    __hip_bfloat16* exch,                         // outbuf + cTC*SLOT
    float* hfp,                                   // d_out + l*64*1024
    int* flags,                                   // [256] dense
    int s0, int nsteps) {
  const int lane = threadIdx.x;
  const int w = blockIdx.x >> 6;
  const int g = blockIdx.x & 63;
  const int l15 = lane & 15, quad = lane >> 4;
  const int u = g * 16 + l15;

  __shared__ short lds[32768 + 256];  // 64 KB n-gate weights + 512 B transpose

  // stage n-gate frags (hi+lo) in fragment order: conflict-free b128 reads
  {
    const __hip_bfloat16* srch = whh_hi_l + ((size_t)(2 * NH) + u) * NH + quad * 8;
    const __hip_bfloat16* srcl = whh_lo_l + (size_t)u * NH + quad * 8;
    short* dst = lds + lane * 8;
#pragma unroll 4
    for (int kc = 0; kc < 32; ++kc) {
      *(short8*)(dst + kc * 512) = ld8(srch + kc * 32);
      *(short8*)(dst + 16384 + kc * 512) = ld8(srcl + kc * 32);
    }
  }
  __syncthreads();

  const int bb = w * 16 + quad * 4;  // first batch row of this lane's acc
  float hreg[4];
#pragma unroll
  for (int r = 0; r < 4; ++r) hreg[r] = hfp[(size_t)(bb + r) * NH + u];

  const float bhr = bhh_l[u], bhz = bhh_l[NH + u], bhn = bhh_l[2 * NH + u];
  const __hip_bfloat16* wr = whh_hi_l + (size_t)u * NH + quad * 8;
  const __hip_bfloat16* wz = whh_hi_l + ((size_t)NH + u) * NH + quad * 8;

  const int* myflag = flags + w * 64 + lane;  // lane watches producer `lane`
  int* outflag = flags + w * 64 + g;

  for (int tc = 0; tc < nsteps; ++tc) {
    const int s = s0 + tc;
    // gi prefetch (in flight during the spin)
    const float* gp = gi_c + ((size_t)tc * NB + bb) * N3H + u;
    float gi_r[4], gi_z[4], gi_n[4];
#pragma unroll
    for (int r = 0; r < 4; ++r) {
      gi_r[r] = gp[(size_t)r * N3H];
      gi_z[r] = gp[(size_t)r * N3H + NH];
      gi_n[r] = gp[(size_t)r * N3H + 2 * NH];
    }

    // wait until all 64 producers of this batch-group published step s-1
    while (true) {
      int fv;
      asm volatile("global_load_dword %0, %1, off sc0 sc1\n\ts_waitcnt vmcnt(0)"
                   : "=v"(fv) : "v"(myflag) : "memory");
      if (fv >= s) break;
      __builtin_amdgcn_s_sleep(1);
    }

    // h A-frags: coalesced LLC-bypass reads (lane-indexed frag-major)
    const short* hrd = (const short*)exch + (size_t)tc * SLOT + w * 16384 + lane * 8;
    short8 hf[32];
#pragma unroll
    for (int kc = 0; kc < 32; ++kc)
      asm volatile("global_load_dwordx4 %0, %1, off sc0 sc1"
                   : "=v"(hf[kc]) : "v"(hrd + kc * 512));
    asm volatile("s_waitcnt vmcnt(24)"
                 : "+v"(hf[0]), "+v"(hf[1]), "+v"(hf[2]), "+v"(hf[3]),
                   "+v"(hf[4]), "+v"(hf[5]), "+v"(hf[6]), "+v"(hf[7]) :: "memory");
    asm volatile("s_waitcnt vmcnt(16)"
                 : "+v"(hf[8]), "+v"(hf[9]), "+v"(hf[10]), "+v"(hf[11]),
                   "+v"(hf[12]), "+v"(hf[13]), "+v"(hf[14]), "+v"(hf[15]) :: "memory");
    asm volatile("s_waitcnt vmcnt(8)"
                 : "+v"(hf[16]), "+v"(hf[17]), "+v"(hf[18]), "+v"(hf[19]),
                   "+v"(hf[20]), "+v"(hf[21]), "+v"(hf[22]), "+v"(hf[23]) :: "memory");
    asm volatile("s_waitcnt vmcnt(0)"
                 : "+v"(hf[24]), "+v"(hf[25]), "+v"(hf[26]), "+v"(hf[27]),
                   "+v"(hf[28]), "+v"(hf[29]), "+v"(hf[30]), "+v"(hf[31]) :: "memory");

    floatx4 accr = {0.f, 0.f, 0.f, 0.f}, accz = accr, accnh = accr, accnl = accr;
#pragma unroll 8
    for (int kc = 0; kc < 32; ++kc) {
      short8 ah = hf[kc];
      short8 brf = ld8(wr + kc * 32);
      short8 bzf = ld8(wz + kc * 32);
      short8 bnh = *(short8*)(lds + lane * 8 + kc * 512);
      short8 bnl = *(short8*)(lds + 16384 + lane * 8 + kc * 512);
      accr = __builtin_amdgcn_mfma_f32_16x16x32_bf16(ah, brf, accr, 0, 0, 0);
      accz = __builtin_amdgcn_mfma_f32_16x16x32_bf16(ah, bzf, accz, 0, 0, 0);
      accnh = __builtin_amdgcn_mfma_f32_16x16x32_bf16(ah, bnh, accnh, 0, 0, 0);
      accnl = __builtin_amdgcn_mfma_f32_16x16x32_bf16(ah, bnl, accnl, 0, 0, 0);
    }

    // epilogue -> LDS transpose tile (frag-major region order)
#pragma unroll
    for (int r = 0; r < 4; ++r) {
      float ghr = accr[r] + bhr;
      float ghz = accz[r] + bhz;
      float ghn = accnh[r] + accnl[r] + bhn;
      float rr = 1.f / (1.f + __expf(-(gi_r[r] + ghr)));
      float zz = 1.f / (1.f + __expf(-(gi_z[r] + ghz)));
      float xt = gi_n[r] + rr * ghn;
      xt = fminf(fmaxf(xt, -15.f), 15.f);
      float e2 = __expf(2.f * xt);
      float nn = (e2 - 1.f) / (e2 + 1.f);
      float hn = (1.f - zz) * nn + zz * hreg[r];
      hreg[r] = hn;
      lds[32768 + ((l15 >> 3) * 16 + quad * 4 + r) * 8 + (l15 & 7)] =
          (short)__builtin_bit_cast(unsigned short, __float2bfloat16(hn));
    }
    __syncthreads();
    if (lane < 32) {
      short8 v = *(short8*)(lds + 32768 + lane * 8);
      const short* wp = (const short*)exch + (size_t)(tc + 1) * SLOT +
                        w * 16384 + g * 256 + lane * 8;
      asm volatile("global_store_dwordx4 %0, %1, off sc0 sc1"
                   :: "v"(wp), "v"(v) : "memory");
    }
    asm volatile("s_waitcnt vmcnt(0)" ::: "memory");  // h visible at LLC
    if (lane == 0) {
      int nv = s + 1;
      asm volatile("global_store_dword %0, %1, off sc0 sc1"
                   :: "v"(outflag), "v"(nv) : "memory");
    }
    __syncthreads();  // keep LDS tile stable until all lanes passed
  }

#pragma unroll
  for (int r = 0; r < 4; ++r) hfp[(size_t)(bb + r) * NH + u] = hreg[r];
}

// ---------------- launch ----------------
extern "C" void kernel_launch(void* const* d_in, const int* in_sizes, int n_in,
                              void* d_out, int out_size, void* d_ws, size_t ws_size,
                              hipStream_t stream) {
  const float* x = (const float*)d_in[0];
  const float* h0 = (const float*)d_in[1];
  const float* w_ih = (const float*)d_in[2];
  const float* w_hh = (const float*)d_in[3];
  const float* b_ih = (const float*)d_in[4];
  const float* b_hh = (const float*)d_in[5];
  float* out = (float*)d_out;
  (void)in_sizes; (void)n_in; (void)out_size;

  char* ws = (char*)d_ws;
  size_t off = 0;
  const size_t wsz = (size_t)NL * N3H * NH * 2;        // 25.2 MB
  const size_t lsz = (size_t)NL * NH * NH * 2;         // 8.4 MB
  const size_t ssz = (size_t)(NT + 1) * SLOT * 2;      // 67.2 MB (513 slots)
  __hip_bfloat16* wih_b = (__hip_bfloat16*)(ws + off); off += wsz;
  __hip_bfloat16* whh_hi = (__hip_bfloat16*)(ws + off); off += wsz;
  __hip_bfloat16* whh_lo = (__hip_bfloat16*)(ws + off); off += lsz;
  __hip_bfloat16* seqA = (__hip_bfloat16*)(ws + off); off += ssz;
  __hip_bfloat16* seqB = (__hip_bfloat16*)(ws + off); off += ssz;
  int* flags = (int*)(ws + off); off += 256 * 4;
  off = (off + 255) & ~(size_t)255;
  float* gi_buf = (float*)(ws + off);

  long long avail = (long long)ws_size - (long long)off;
  int TC = 256;
  while (TC > 2 && (long long)TC * NB * N3H * 4 > avail) TC >>= 1;

  {
    size_t n = (size_t)NL * N3H * NH;
    conv_w_kernel<<<dim3((n + 255) / 256), dim3(256), 0, stream>>>(
        w_ih, w_hh, wih_b, whh_hi, whh_lo);
  }
  {
    size_t n = (size_t)NT * NB * NH;
    conv_x_kernel<<<dim3((n + 255) / 256), dim3(256), 0, stream>>>(x, seqA);
  }
  {
    size_t n = (size_t)NL * NB * NH;
    init_out_kernel<<<dim3((n + 255) / 256), dim3(256), 0, stream>>>(h0, out, flags);
  }

  const size_t bh = (size_t)NB * NH;
  const int nchunks = NT / TC;
  for (int l = 0; l < NL; ++l) {
    __hip_bfloat16* inbuf = (l & 1) ? seqB : seqA;
    __hip_bfloat16* outbuf = (l & 1) ? seqA : seqB;
    init_hbf_kernel<<<dim3((int)((bh + 255) / 256)), dim3(256), 0, stream>>>(
        h0 + (size_t)l * bh, outbuf);  // slot 0 = h0 (frag-major)
    const __hip_bfloat16* wih_l = wih_b + (size_t)l * N3H * NH;
    const __hip_bfloat16* whha_l = whh_hi + (size_t)l * N3H * NH;
    const __hip_bfloat16* whhb_l = whh_lo + (size_t)l * NH * NH;
    const float* bih_l = b_ih + (size_t)l * N3H;
    const float* bhh_l = b_hh + (size_t)l * N3H;
    float* hfp_l = out + (size_t)l * bh;
    for (int c = 0; c < nchunks; ++c) {
      const __hip_bfloat16* Aslot = inbuf + (size_t)(1 + c * TC) * SLOT;
      gemm_gi_kernel<<<dim3(TC * 64 / 128, N3H / 128), dim3(256), 0, stream>>>(
          Aslot, wih_l, bih_l, gi_buf);
      gru_persist_kernel<<<dim3(256), dim3(64), 0, stream>>>(
          whha_l, whhb_l, gi_buf, bhh_l,
          outbuf + (size_t)(c * TC) * SLOT, hfp_l, flags,
          l * NT + c * TC, TC);
    }
  }
}